// Round 5
// baseline (125.439 us; speedup 1.0000x reference)
//
#include <hip/hip_runtime.h>
#include <math.h>

#define NB 8
#define NN 2048
#define ND 256

typedef _Float16 f16;
typedef f16 f16x8 __attribute__((ext_vector_type(8)));
typedef f16 f16x4 __attribute__((ext_vector_type(4)));
typedef float f32x4 __attribute__((ext_vector_type(4)));

static constexpr float EPS = 1e-6f;

// ---- k_prep: x -> (hi,lo) fp16 split + partial sum/sumsq + row norms ------
__global__ __launch_bounds__(256) void k_prep(const float* __restrict__ x,
                                              f16* __restrict__ xh, f16* __restrict__ xl,
                                              float* __restrict__ partS,
                                              float* __restrict__ partSS,
                                              float* __restrict__ sq) {
    int b = blockIdx.y, ch = blockIdx.x;
    int t = threadIdx.x;
    int c = t & 63, rg = t >> 6;
    size_t base = ((size_t)b * NN + (size_t)ch * 64) * ND;
    float s0 = 0.f, s1 = 0.f, s2 = 0.f, s3 = 0.f;
    float q0 = 0.f, q1 = 0.f, q2 = 0.f, q3 = 0.f;
    for (int r = rg; r < 64; r += 4) {
        float4 v = *(const float4*)&x[base + (size_t)r * ND + c * 4];
        s0 += v.x; s1 += v.y; s2 += v.z; s3 += v.w;
        float p = v.x * v.x + v.y * v.y + v.z * v.z + v.w * v.w;
        q0 += v.x * v.x; q1 += v.y * v.y; q2 += v.z * v.z; q3 += v.w * v.w;
        f16 h0 = (f16)v.x, h1 = (f16)v.y, h2 = (f16)v.z, h3 = (f16)v.w;
        f16x4 hv = {h0, h1, h2, h3};
        f16x4 lv = {(f16)(v.x - (float)h0), (f16)(v.y - (float)h1),
                    (f16)(v.z - (float)h2), (f16)(v.w - (float)h3)};
        *(f16x4*)&xh[base + (size_t)r * ND + c * 4] = hv;
        *(f16x4*)&xl[base + (size_t)r * ND + c * 4] = lv;
        #pragma unroll
        for (int off = 32; off > 0; off >>= 1) p += __shfl_xor(p, off, 64);
        if (c == 0) sq[b * NN + ch * 64 + r] = p;
    }
    __shared__ float rS[4][64][4];
    __shared__ float rQ[4][64][4];
    rS[rg][c][0] = s0; rS[rg][c][1] = s1; rS[rg][c][2] = s2; rS[rg][c][3] = s3;
    rQ[rg][c][0] = q0; rQ[rg][c][1] = q1; rQ[rg][c][2] = q2; rQ[rg][c][3] = q3;
    __syncthreads();
    if (rg == 0) {
        #pragma unroll
        for (int e = 0; e < 4; ++e) {
            float S = rS[0][c][e] + rS[1][c][e] + rS[2][c][e] + rS[3][c][e];
            float Q = rQ[0][c][e] + rQ[1][c][e] + rQ[2][c][e] + rQ[3][c][e];
            partS[(b * 32 + ch) * ND + c * 4 + e] = S;
            partSS[(b * 32 + ch) * ND + c * 4 + e] = Q;
        }
    }
}

// ---- k_scale: sigma -> sc; em[b][n] = exp(-sq*sc) -------------------------
__global__ __launch_bounds__(256) void k_scale(const float* __restrict__ partS,
                                               const float* __restrict__ partSS,
                                               const float* __restrict__ sq,
                                               float* __restrict__ scale,
                                               float* __restrict__ em) {
    int b = blockIdx.x, d = threadIdx.x;
    float s = 0.f, ss = 0.f;
    for (int ch = 0; ch < 32; ++ch) {
        s += partS[(b * 32 + ch) * ND + d];
        ss += partSS[(b * 32 + ch) * ND + d];
    }
    float mean = s * (1.0f / NN);
    float var = ss * (1.0f / NN) - mean * mean;
    float sd = sqrtf(fmaxf(var, 0.f));
    __shared__ float red[256];
    __shared__ float s_sc;
    red[d] = sd;
    __syncthreads();
    for (int off = 128; off > 0; off >>= 1) {
        if (d < off) red[d] += red[d + off];
        __syncthreads();
    }
    if (d == 0) {
        float sigma = red[0] * (1.0f / ND) + EPS;
        double c = pow(4.0 / (ND + 2), 1.0 / (ND + 4)) * pow((double)NN, -1.0 / (ND + 4));
        float h = (float)c * sigma + EPS;
        s_sc = 1.0f / ((float)ND * (2.0f * h * h + EPS));
        scale[b] = s_sc;
    }
    __syncthreads();
    float sc = s_sc;
    for (int n = d; n < NN; n += 256) em[b * NN + n] = __expf(-sq[b * NN + n] * sc);
}

// ---- k_dens: symmetric split-fp16 MFMA, register fragments, no LDS stage --
// Upper-triangular 128x128 tile pairs (i<=j). Fragments loaded straight from
// L2 (per-batch working set 2.1 MB fits one XCD L2; grid pins batch to XCD).
// No barriers in the K-loop -> compiler interleaves MFMA with loads.
__global__ __launch_bounds__(256, 2) void k_dens(const f16* __restrict__ xh,
                                                 const f16* __restrict__ xl,
                                                 const float* __restrict__ em,
                                                 const float* __restrict__ scale,
                                                 float* __restrict__ dens_part) {
    int wg = blockIdx.x;
    int b = wg & 7;          // batch -> XCD pin (wg%8 round-robin)
    int t = wg >> 3;         // triangular tile index 0..135
    int ti = 0, basec = 0;
    while (t >= basec + (16 - ti)) { basec += 16 - ti; ++ti; }
    int tj = ti + (t - basec);
    int n0 = ti * 128;
    int m0 = tj * 128;

    int tid = threadIdx.x;
    int w = tid >> 6, lane = tid & 63;
    int wr = w >> 1, wc = w & 1;

    __shared__ float dl[2][128];
    __shared__ float dc[2][128];

    const size_t xb = (size_t)b * NN * ND;
    const f16* gAh = xh + xb;
    const f16* gAl = xl + xb;

    // per-lane fragment base offsets (f16 units): row*ND + kchunk*8
    size_t aOff[4], bOff[4];
    #pragma unroll
    for (int i = 0; i < 4; ++i) {
        aOff[i] = (size_t)(n0 + wr * 64 + i * 16 + (lane & 15)) * ND + (lane >> 4) * 8;
        bOff[i] = (size_t)(m0 + wc * 64 + i * 16 + (lane & 15)) * ND + (lane >> 4) * 8;
    }

    f32x4 acc[4][4];
    #pragma unroll
    for (int i = 0; i < 4; ++i)
        #pragma unroll
        for (int j = 0; j < 4; ++j)
            acc[i][j] = (f32x4){0.f, 0.f, 0.f, 0.f};

    #pragma unroll 2
    for (int kt = 0; kt < ND / 32; ++kt) {
        int k0 = kt * 32;
        f16x8 ah[4], al[4], bh[4], bl[4];
        #pragma unroll
        for (int i = 0; i < 4; ++i) {
            ah[i] = *(const f16x8*)(gAh + aOff[i] + k0);
            al[i] = *(const f16x8*)(gAl + aOff[i] + k0);
            bh[i] = *(const f16x8*)(gAh + bOff[i] + k0);
            bl[i] = *(const f16x8*)(gAl + bOff[i] + k0);
        }
        #pragma unroll
        for (int i = 0; i < 4; ++i)
            #pragma unroll
            for (int j = 0; j < 4; ++j) {
                acc[i][j] = __builtin_amdgcn_mfma_f32_16x16x32_f16(ah[i], bh[j], acc[i][j], 0, 0, 0);
                acc[i][j] = __builtin_amdgcn_mfma_f32_16x16x32_f16(ah[i], bl[j], acc[i][j], 0, 0, 0);
                acc[i][j] = __builtin_amdgcn_mfma_f32_16x16x32_f16(al[i], bh[j], acc[i][j], 0, 0, 0);
            }
    }

    // epilogue: K = exp(2sc*dot); row-part += em[col]*K ; col-part += em[row]*K
    float sc2 = 2.0f * scale[b];
    float emv[4];
    #pragma unroll
    for (int j = 0; j < 4; ++j)
        emv[j] = em[b * NN + m0 + wc * 64 + j * 16 + (lane & 15)];
    float emn[4][4];
    #pragma unroll
    for (int i = 0; i < 4; ++i) {
        float4 v = *(const float4*)&em[b * NN + n0 + wr * 64 + i * 16 + (lane >> 4) * 4];
        emn[i][0] = v.x; emn[i][1] = v.y; emn[i][2] = v.z; emn[i][3] = v.w;
    }

    float colsum[4] = {0.f, 0.f, 0.f, 0.f};
    #pragma unroll
    for (int i = 0; i < 4; ++i)
        #pragma unroll
        for (int e = 0; e < 4; ++e) {
            float rs = 0.f;
            #pragma unroll
            for (int j = 0; j < 4; ++j) {
                float v = __expf(sc2 * acc[i][j][e]);
                rs += emv[j] * v;
                colsum[j] += emn[i][e] * v;
            }
            rs += __shfl_xor(rs, 1, 64);
            rs += __shfl_xor(rs, 2, 64);
            rs += __shfl_xor(rs, 4, 64);
            rs += __shfl_xor(rs, 8, 64);
            if ((lane & 15) == 0)
                dl[wc][wr * 64 + i * 16 + (lane >> 4) * 4 + e] = rs;
        }
    #pragma unroll
    for (int j = 0; j < 4; ++j) {
        float cs = colsum[j];
        cs += __shfl_xor(cs, 16, 64);
        cs += __shfl_xor(cs, 32, 64);
        if ((lane >> 4) == 0)
            dc[wr][wc * 64 + j * 16 + (lane & 15)] = cs;
    }
    __syncthreads();
    if (tid < 128) {
        dens_part[((size_t)(b * 16) + tj) * NN + n0 + tid] = dl[0][tid] + dl[1][tid];
    } else if (ti != tj) {
        int c = tid - 128;
        dens_part[((size_t)(b * 16) + ti) * NN + m0 + c] = dc[0][c] + dc[1][c];
    }
}

// ---- k_dsum: dens = em*sum(16 partials) + per-block density sum -----------
// grid (8, NB): 256 n per block.
__global__ __launch_bounds__(256) void k_dsum(const float* __restrict__ part,
                                              const float* __restrict__ em,
                                              float* __restrict__ dens,
                                              float* __restrict__ psum) {
    int b = blockIdx.y;
    int n = blockIdx.x * 256 + threadIdx.x;
    int t = threadIdx.x;
    float s = 0.f;
    #pragma unroll
    for (int mt = 0; mt < 16; ++mt) s += part[((size_t)(b * 16 + mt)) * NN + n];
    s *= em[b * NN + n];
    dens[b * NN + n] = s;
    __shared__ float red[256];
    red[t] = s;
    __syncthreads();
    for (int off = 128; off > 0; off >>= 1) {
        if (t < off) red[t] += red[t + off];
        __syncthreads();
    }
    if (t == 0) psum[b * 8 + blockIdx.x] = red[0];
}

// ---- k_dstats: mean from psum; two-pass var over dens (L2-hot); thr -------
__global__ __launch_bounds__(256) void k_dstats(const float* __restrict__ dens,
                                                const float* __restrict__ psum,
                                                float* __restrict__ thr) {
    int b = blockIdx.x, t = threadIdx.x;
    float tot = 0.f;
    #pragma unroll
    for (int i = 0; i < 8; ++i) tot += psum[b * 8 + i];
    float mean = tot * (1.0f / NN);
    float vs = 0.f;
    #pragma unroll
    for (int i = 0; i < 8; ++i) {
        float d2 = dens[b * NN + t + i * 256] - mean;
        vs += d2 * d2;
    }
    __shared__ float red[256];
    red[t] = vs;
    __syncthreads();
    for (int off = 128; off > 0; off >>= 1) {
        if (t < off) red[t] += red[t + off];
        __syncthreads();
    }
    if (t == 0) thr[b] = mean - 2.0f * sqrtf(red[0] / (float)(NN - 1));
}

// ---- k_maskpart: masked partial feature sums (vectorized) -----------------
__global__ __launch_bounds__(256) void k_maskpart(const float* __restrict__ x,
                                                  const float* __restrict__ dens,
                                                  const float* __restrict__ thr,
                                                  float* __restrict__ partM,
                                                  int* __restrict__ partC) {
    int b = blockIdx.y, ch = blockIdx.x;
    int t = threadIdx.x;
    int c = t & 63, rg = t >> 6;
    float tv = thr[b];
    float s0 = 0.f, s1 = 0.f, s2 = 0.f, s3 = 0.f;
    int cnt = 0;
    for (int r = rg; r < 128; r += 4) {
        int n = ch * 128 + r;
        if (dens[b * NN + n] > tv) {
            float4 v = *(const float4*)&x[((size_t)b * NN + n) * ND + c * 4];
            s0 += v.x; s1 += v.y; s2 += v.z; s3 += v.w;
            ++cnt;
        }
    }
    __shared__ float rS[4][64][4];
    __shared__ int rC[4];
    rS[rg][c][0] = s0; rS[rg][c][1] = s1; rS[rg][c][2] = s2; rS[rg][c][3] = s3;
    if (c == 0) rC[rg] = cnt;
    __syncthreads();
    if (rg == 0) {
        #pragma unroll
        for (int e = 0; e < 4; ++e) {
            float S = rS[0][c][e] + rS[1][c][e] + rS[2][c][e] + rS[3][c][e];
            partM[(b * 16 + ch) * ND + c * 4 + e] = S;
        }
        if (c == 0) partC[b * 16 + ch] = rC[0] + rC[1] + rC[2] + rC[3];
    }
}

// ---- k_out: combine --------------------------------------------------------
__global__ __launch_bounds__(256) void k_out(const float* __restrict__ partM,
                                             const int* __restrict__ partC,
                                             float* __restrict__ out) {
    int b = blockIdx.x, d = threadIdx.x;
    float s = 0.f;
    int cnt = 0;
    for (int ch = 0; ch < 16; ++ch) {
        s += partM[(b * 16 + ch) * ND + d];
        cnt += partC[b * 16 + ch];
    }
    out[b * ND + d] = (cnt > 0) ? s / (float)max(cnt, 1) : 0.f;
}

extern "C" void kernel_launch(void* const* d_in, const int* in_sizes, int n_in,
                              void* d_out, int out_size, void* d_ws, size_t ws_size,
                              hipStream_t stream) {
    const float* x = (const float*)d_in[0];
    float* out = (float*)d_out;

    char* p = (char*)d_ws;
    f16* xh = (f16*)p;            p += (size_t)NB * NN * ND * 2;
    f16* xl = (f16*)p;            p += (size_t)NB * NN * ND * 2;
    float* sq = (float*)p;        p += (size_t)NB * NN * 4;
    float* em = (float*)p;        p += (size_t)NB * NN * 4;
    float* partS = (float*)p;     p += (size_t)NB * 32 * ND * 4;
    float* partSS = (float*)p;    p += (size_t)NB * 32 * ND * 4;
    float* scale = (float*)p;     p += 256;
    float* dens_part = (float*)p; p += (size_t)NB * 16 * NN * 4;
    float* dens = (float*)p;      p += (size_t)NB * NN * 4;
    float* psum = (float*)p;      p += 256;
    float* thr = (float*)p;       p += 256;
    float* partM = (float*)p;     p += (size_t)NB * 16 * ND * 4;
    int* partC = (int*)p;         p += (size_t)NB * 16 * 4;

    k_prep<<<dim3(32, NB), 256, 0, stream>>>(x, xh, xl, partS, partSS, sq);
    k_scale<<<NB, 256, 0, stream>>>(partS, partSS, sq, scale, em);
    k_dens<<<136 * NB, 256, 0, stream>>>(xh, xl, em, scale, dens_part);
    k_dsum<<<dim3(8, NB), 256, 0, stream>>>(dens_part, em, dens, psum);
    k_dstats<<<NB, 256, 0, stream>>>(dens, psum, thr);
    k_maskpart<<<dim3(16, NB), 256, 0, stream>>>(x, dens, thr, partM, partC);
    k_out<<<NB, 256, 0, stream>>>(partM, partC, out);
}

// Round 6
// 98.251 us; speedup vs baseline: 1.2767x; 1.2767x over previous
//
#include <hip/hip_runtime.h>
#include <math.h>

#define NB 8
#define NN 2048
#define ND 256

typedef _Float16 f16;
typedef f16 f16x8 __attribute__((ext_vector_type(8)));
typedef f16 f16x4 __attribute__((ext_vector_type(4)));
typedef float f32x4 __attribute__((ext_vector_type(4)));

static constexpr float EPS = 1e-6f;

__device__ __forceinline__ void gload16(const void* g, void* l) {
    __builtin_amdgcn_global_load_lds(
        (const __attribute__((address_space(1))) unsigned int*)g,
        (__attribute__((address_space(3))) unsigned int*)l, 16, 0, 0);
}

// ---- k_prep: x -> (hi,lo) fp16 split + partial sum/sumsq + row norms ------
__global__ __launch_bounds__(256) void k_prep(const float* __restrict__ x,
                                              f16* __restrict__ xh, f16* __restrict__ xl,
                                              float* __restrict__ partS,
                                              float* __restrict__ partSS,
                                              float* __restrict__ sq) {
    int b = blockIdx.y, ch = blockIdx.x;
    int t = threadIdx.x;
    int c = t & 63, rg = t >> 6;
    size_t base = ((size_t)b * NN + (size_t)ch * 64) * ND;
    float s0 = 0.f, s1 = 0.f, s2 = 0.f, s3 = 0.f;
    float q0 = 0.f, q1 = 0.f, q2 = 0.f, q3 = 0.f;
    for (int r = rg; r < 64; r += 4) {
        float4 v = *(const float4*)&x[base + (size_t)r * ND + c * 4];
        s0 += v.x; s1 += v.y; s2 += v.z; s3 += v.w;
        float p = v.x * v.x + v.y * v.y + v.z * v.z + v.w * v.w;
        q0 += v.x * v.x; q1 += v.y * v.y; q2 += v.z * v.z; q3 += v.w * v.w;
        f16 h0 = (f16)v.x, h1 = (f16)v.y, h2 = (f16)v.z, h3 = (f16)v.w;
        f16x4 hv = {h0, h1, h2, h3};
        f16x4 lv = {(f16)(v.x - (float)h0), (f16)(v.y - (float)h1),
                    (f16)(v.z - (float)h2), (f16)(v.w - (float)h3)};
        *(f16x4*)&xh[base + (size_t)r * ND + c * 4] = hv;
        *(f16x4*)&xl[base + (size_t)r * ND + c * 4] = lv;
        #pragma unroll
        for (int off = 32; off > 0; off >>= 1) p += __shfl_xor(p, off, 64);
        if (c == 0) sq[b * NN + ch * 64 + r] = p;
    }
    __shared__ float rS[4][64][4];
    __shared__ float rQ[4][64][4];
    rS[rg][c][0] = s0; rS[rg][c][1] = s1; rS[rg][c][2] = s2; rS[rg][c][3] = s3;
    rQ[rg][c][0] = q0; rQ[rg][c][1] = q1; rQ[rg][c][2] = q2; rQ[rg][c][3] = q3;
    __syncthreads();
    if (rg == 0) {
        #pragma unroll
        for (int e = 0; e < 4; ++e) {
            float S = rS[0][c][e] + rS[1][c][e] + rS[2][c][e] + rS[3][c][e];
            float Q = rQ[0][c][e] + rQ[1][c][e] + rQ[2][c][e] + rQ[3][c][e];
            partS[(b * 32 + ch) * ND + c * 4 + e] = S;
            partSS[(b * 32 + ch) * ND + c * 4 + e] = Q;
        }
    }
}

// ---- k_scale: sigma -> sc; em[b][n] = exp(-sq*sc) -------------------------
__global__ __launch_bounds__(256) void k_scale(const float* __restrict__ partS,
                                               const float* __restrict__ partSS,
                                               const float* __restrict__ sq,
                                               float* __restrict__ scale,
                                               float* __restrict__ em) {
    int b = blockIdx.x, d = threadIdx.x;
    float s = 0.f, ss = 0.f;
    for (int ch = 0; ch < 32; ++ch) {
        s += partS[(b * 32 + ch) * ND + d];
        ss += partSS[(b * 32 + ch) * ND + d];
    }
    float mean = s * (1.0f / NN);
    float var = ss * (1.0f / NN) - mean * mean;
    float sd = sqrtf(fmaxf(var, 0.f));
    __shared__ float red[256];
    __shared__ float s_sc;
    red[d] = sd;
    __syncthreads();
    for (int off = 128; off > 0; off >>= 1) {
        if (d < off) red[d] += red[d + off];
        __syncthreads();
    }
    if (d == 0) {
        float sigma = red[0] * (1.0f / ND) + EPS;
        double c = pow(4.0 / (ND + 2), 1.0 / (ND + 4)) * pow((double)NN, -1.0 / (ND + 4));
        float h = (float)c * sigma + EPS;
        s_sc = 1.0f / ((float)ND * (2.0f * h * h + EPS));
        scale[b] = s_sc;
    }
    __syncthreads();
    float sc = s_sc;
    for (int n = d; n < NN; n += 256) em[b * NN + n] = __expf(-sq[b * NN + n] * sc);
}

// ---- k_dens: symmetric split-fp16 MFMA GEMM, hybrid operand feed ----------
// hi operands staged in LDS (shared 2x between waves, swizzled); lo operands
// loaded per-wave straight from L2 into VGPRs (latency folds into the same
// barrier drain as the hi staging). Upper-triangular 128x128 tile pairs.
__global__ __launch_bounds__(256, 3) void k_dens(const f16* __restrict__ xh,
                                                 const f16* __restrict__ xl,
                                                 const float* __restrict__ em,
                                                 const float* __restrict__ scale,
                                                 float* __restrict__ dens_part) {
    int b = blockIdx.y;
    int t = blockIdx.x;
    int ti = 0, basec = 0;
    while (t >= basec + (16 - ti)) { basec += 16 - ti; ++ti; }
    int tj = ti + (t - basec);
    int n0 = ti * 128;
    int m0 = tj * 128;

    int tid = threadIdx.x;
    int w = tid >> 6, lane = tid & 63;
    int wr = w >> 1, wc = w & 1;

    __shared__ alignas(16) f16 sAh[128 * 32];
    __shared__ alignas(16) f16 sBh[128 * 32];
    __shared__ float dl[2][128];
    __shared__ float dc[2][128];

    const size_t xb = (size_t)b * NN * ND;
    const f16* gAh = xh + xb + (size_t)n0 * ND;
    const f16* gBh = xh + xb + (size_t)m0 * ND;
    const f16* gL  = xl + xb;              // lo: absolute row addressing

    // ds_read byte offsets (row stride 64B, 16B chunks, XOR-swizzled)
    int offA[4], offB[4];
    #pragma unroll
    for (int i = 0; i < 4; ++i) {
        int rA = wr * 64 + i * 16 + (lane & 15);
        offA[i] = rA * 64 + (((lane >> 4) * 16) ^ (((rA >> 1) & 3) << 4));
        int rB = wc * 64 + i * 16 + (lane & 15);
        offB[i] = rB * 64 + (((lane >> 4) * 16) ^ (((rB >> 1) & 3) << 4));
    }
    // global lo fragment offsets (f16 units) — verified in round-4 kernel
    size_t aOff[4], bOff[4];
    #pragma unroll
    for (int i = 0; i < 4; ++i) {
        aOff[i] = (size_t)(n0 + wr * 64 + i * 16 + (lane & 15)) * ND + (lane >> 4) * 8;
        bOff[i] = (size_t)(m0 + wc * 64 + i * 16 + (lane & 15)) * ND + (lane >> 4) * 8;
    }

    f32x4 acc[4][4];
    #pragma unroll
    for (int i = 0; i < 4; ++i)
        #pragma unroll
        for (int j = 0; j < 4; ++j)
            acc[i][j] = (f32x4){0.f, 0.f, 0.f, 0.f};

    for (int kt = 0; kt < ND / 32; ++kt) {
        int k0 = kt * 32;
        // stage hi tiles to LDS (linear dest, inverse-swizzled source)
        #pragma unroll
        for (int pass = 0; pass < 2; ++pass) {
            int f = pass * 256 + w * 64 + lane;
            int row = f >> 2;
            int c = f & 3;
            int col = ((c ^ ((row >> 1) & 3)) << 3);
            size_t go = (size_t)row * ND + k0 + col;
            int lo_ = pass * 2048 + w * 512;
            gload16(gAh + go, sAh + lo_);
            gload16(gBh + go, sBh + lo_);
        }
        // lo fragments: global (L2) -> VGPR, per wave
        f16x8 al[4], bl[4];
        #pragma unroll
        for (int i = 0; i < 4; ++i) {
            al[i] = *(const f16x8*)(gL + aOff[i] + k0);
            bl[i] = *(const f16x8*)(gL + bOff[i] + k0);
        }
        __syncthreads();               // drains staging DMA + lo loads

        f16x8 ah[4], bh[4];
        #pragma unroll
        for (int i = 0; i < 4; ++i) {
            ah[i] = *(const f16x8*)((const char*)sAh + offA[i]);
            bh[i] = *(const f16x8*)((const char*)sBh + offB[i]);
        }
        #pragma unroll
        for (int i = 0; i < 4; ++i)
            #pragma unroll
            for (int j = 0; j < 4; ++j) {
                acc[i][j] = __builtin_amdgcn_mfma_f32_16x16x32_f16(ah[i], bh[j], acc[i][j], 0, 0, 0);
                acc[i][j] = __builtin_amdgcn_mfma_f32_16x16x32_f16(ah[i], bl[j], acc[i][j], 0, 0, 0);
                acc[i][j] = __builtin_amdgcn_mfma_f32_16x16x32_f16(al[i], bh[j], acc[i][j], 0, 0, 0);
            }
        __syncthreads();               // LDS reuse guard
    }

    // epilogue: K = exp(2sc*dot); row-part += em[col]*K ; col-part += em[row]*K
    float sc2 = 2.0f * scale[b];
    float emv[4];
    #pragma unroll
    for (int j = 0; j < 4; ++j)
        emv[j] = em[b * NN + m0 + wc * 64 + j * 16 + (lane & 15)];
    float emn[4][4];
    #pragma unroll
    for (int i = 0; i < 4; ++i) {
        float4 v = *(const float4*)&em[b * NN + n0 + wr * 64 + i * 16 + (lane >> 4) * 4];
        emn[i][0] = v.x; emn[i][1] = v.y; emn[i][2] = v.z; emn[i][3] = v.w;
    }

    float colsum[4] = {0.f, 0.f, 0.f, 0.f};
    #pragma unroll
    for (int i = 0; i < 4; ++i)
        #pragma unroll
        for (int e = 0; e < 4; ++e) {
            float rs = 0.f;
            #pragma unroll
            for (int j = 0; j < 4; ++j) {
                float v = __expf(sc2 * acc[i][j][e]);
                rs += emv[j] * v;
                colsum[j] += emn[i][e] * v;
            }
            rs += __shfl_xor(rs, 1, 64);
            rs += __shfl_xor(rs, 2, 64);
            rs += __shfl_xor(rs, 4, 64);
            rs += __shfl_xor(rs, 8, 64);
            if ((lane & 15) == 0)
                dl[wc][wr * 64 + i * 16 + (lane >> 4) * 4 + e] = rs;
        }
    #pragma unroll
    for (int j = 0; j < 4; ++j) {
        float cs = colsum[j];
        cs += __shfl_xor(cs, 16, 64);
        cs += __shfl_xor(cs, 32, 64);
        if ((lane >> 4) == 0)
            dc[wr][wc * 64 + j * 16 + (lane & 15)] = cs;
    }
    __syncthreads();
    if (tid < 128) {
        dens_part[((size_t)(b * 16) + tj) * NN + n0 + tid] = dl[0][tid] + dl[1][tid];
    } else if (ti != tj) {
        int c = tid - 128;
        dens_part[((size_t)(b * 16) + ti) * NN + m0 + c] = dc[0][c] + dc[1][c];
    }
}

// ---- k_dsum: dens = em*sum(16 partials) + per-block density sum -----------
__global__ __launch_bounds__(256) void k_dsum(const float* __restrict__ part,
                                              const float* __restrict__ em,
                                              float* __restrict__ dens,
                                              float* __restrict__ psum) {
    int b = blockIdx.y;
    int n = blockIdx.x * 256 + threadIdx.x;
    int t = threadIdx.x;
    float s = 0.f;
    #pragma unroll
    for (int mt = 0; mt < 16; ++mt) s += part[((size_t)(b * 16 + mt)) * NN + n];
    s *= em[b * NN + n];
    dens[b * NN + n] = s;
    __shared__ float red[256];
    red[t] = s;
    __syncthreads();
    for (int off = 128; off > 0; off >>= 1) {
        if (t < off) red[t] += red[t + off];
        __syncthreads();
    }
    if (t == 0) psum[b * 8 + blockIdx.x] = red[0];
}

// ---- k_dstats: mean from psum; two-pass var over dens (L2-hot); thr -------
__global__ __launch_bounds__(256) void k_dstats(const float* __restrict__ dens,
                                                const float* __restrict__ psum,
                                                float* __restrict__ thr) {
    int b = blockIdx.x, t = threadIdx.x;
    float tot = 0.f;
    #pragma unroll
    for (int i = 0; i < 8; ++i) tot += psum[b * 8 + i];
    float mean = tot * (1.0f / NN);
    float vs = 0.f;
    #pragma unroll
    for (int i = 0; i < 8; ++i) {
        float d2 = dens[b * NN + t + i * 256] - mean;
        vs += d2 * d2;
    }
    __shared__ float red[256];
    red[t] = vs;
    __syncthreads();
    for (int off = 128; off > 0; off >>= 1) {
        if (t < off) red[t] += red[t + off];
        __syncthreads();
    }
    if (t == 0) thr[b] = mean - 2.0f * sqrtf(red[0] / (float)(NN - 1));
}

// ---- k_maskpart: masked partial feature sums (vectorized) -----------------
__global__ __launch_bounds__(256) void k_maskpart(const float* __restrict__ x,
                                                  const float* __restrict__ dens,
                                                  const float* __restrict__ thr,
                                                  float* __restrict__ partM,
                                                  int* __restrict__ partC) {
    int b = blockIdx.y, ch = blockIdx.x;
    int t = threadIdx.x;
    int c = t & 63, rg = t >> 6;
    float tv = thr[b];
    float s0 = 0.f, s1 = 0.f, s2 = 0.f, s3 = 0.f;
    int cnt = 0;
    for (int r = rg; r < 128; r += 4) {
        int n = ch * 128 + r;
        if (dens[b * NN + n] > tv) {
            float4 v = *(const float4*)&x[((size_t)b * NN + n) * ND + c * 4];
            s0 += v.x; s1 += v.y; s2 += v.z; s3 += v.w;
            ++cnt;
        }
    }
    __shared__ float rS[4][64][4];
    __shared__ int rC[4];
    rS[rg][c][0] = s0; rS[rg][c][1] = s1; rS[rg][c][2] = s2; rS[rg][c][3] = s3;
    if (c == 0) rC[rg] = cnt;
    __syncthreads();
    if (rg == 0) {
        #pragma unroll
        for (int e = 0; e < 4; ++e) {
            float S = rS[0][c][e] + rS[1][c][e] + rS[2][c][e] + rS[3][c][e];
            partM[(b * 16 + ch) * ND + c * 4 + e] = S;
        }
        if (c == 0) partC[b * 16 + ch] = rC[0] + rC[1] + rC[2] + rC[3];
    }
}

// ---- k_out: combine --------------------------------------------------------
__global__ __launch_bounds__(256) void k_out(const float* __restrict__ partM,
                                             const int* __restrict__ partC,
                                             float* __restrict__ out) {
    int b = blockIdx.x, d = threadIdx.x;
    float s = 0.f;
    int cnt = 0;
    for (int ch = 0; ch < 16; ++ch) {
        s += partM[(b * 16 + ch) * ND + d];
        cnt += partC[b * 16 + ch];
    }
    out[b * ND + d] = (cnt > 0) ? s / (float)max(cnt, 1) : 0.f;
}

extern "C" void kernel_launch(void* const* d_in, const int* in_sizes, int n_in,
                              void* d_out, int out_size, void* d_ws, size_t ws_size,
                              hipStream_t stream) {
    const float* x = (const float*)d_in[0];
    float* out = (float*)d_out;

    char* p = (char*)d_ws;
    f16* xh = (f16*)p;            p += (size_t)NB * NN * ND * 2;
    f16* xl = (f16*)p;            p += (size_t)NB * NN * ND * 2;
    float* sq = (float*)p;        p += (size_t)NB * NN * 4;
    float* em = (float*)p;        p += (size_t)NB * NN * 4;
    float* partS = (float*)p;     p += (size_t)NB * 32 * ND * 4;
    float* partSS = (float*)p;    p += (size_t)NB * 32 * ND * 4;
    float* scale = (float*)p;     p += 256;
    float* dens_part = (float*)p; p += (size_t)NB * 16 * NN * 4;
    float* dens = (float*)p;      p += (size_t)NB * NN * 4;
    float* psum = (float*)p;      p += 256;
    float* thr = (float*)p;       p += 256;
    float* partM = (float*)p;     p += (size_t)NB * 16 * ND * 4;
    int* partC = (int*)p;         p += (size_t)NB * 16 * 4;

    k_prep<<<dim3(32, NB), 256, 0, stream>>>(x, xh, xl, partS, partSS, sq);
    k_scale<<<NB, 256, 0, stream>>>(partS, partSS, sq, scale, em);
    k_dens<<<dim3(136, NB), 256, 0, stream>>>(xh, xl, em, scale, dens_part);
    k_dsum<<<dim3(8, NB), 256, 0, stream>>>(dens_part, em, dens, psum);
    k_dstats<<<NB, 256, 0, stream>>>(dens, psum, thr);
    k_maskpart<<<dim3(16, NB), 256, 0, stream>>>(x, dens, thr, partM, partC);
    k_out<<<NB, 256, 0, stream>>>(partM, partC, out);
}

// Round 7
// 85.221 us; speedup vs baseline: 1.4719x; 1.1529x over previous
//
#include <hip/hip_runtime.h>
#include <math.h>

#define NB 8
#define NN 2048
#define ND 256

typedef _Float16 f16;
typedef f16 f16x8 __attribute__((ext_vector_type(8)));
typedef f16 f16x4 __attribute__((ext_vector_type(4)));
typedef float f32x4 __attribute__((ext_vector_type(4)));

static constexpr float EPS = 1e-6f;

__device__ __forceinline__ void gload16(const void* g, void* l) {
    __builtin_amdgcn_global_load_lds(
        (const __attribute__((address_space(1))) unsigned int*)g,
        (__attribute__((address_space(3))) unsigned int*)l, 16, 0, 0);
}

// ---- k_prep: x -> (hi,lo) fp16 split + partial sum/sumsq + row norms ------
__global__ __launch_bounds__(256) void k_prep(const float* __restrict__ x,
                                              f16* __restrict__ xh, f16* __restrict__ xl,
                                              float* __restrict__ partS,
                                              float* __restrict__ partSS,
                                              float* __restrict__ sq) {
    int b = blockIdx.y, ch = blockIdx.x;
    int t = threadIdx.x;
    int c = t & 63, rg = t >> 6;
    size_t base = ((size_t)b * NN + (size_t)ch * 64) * ND;
    float s0 = 0.f, s1 = 0.f, s2 = 0.f, s3 = 0.f;
    float q0 = 0.f, q1 = 0.f, q2 = 0.f, q3 = 0.f;
    for (int r = rg; r < 64; r += 4) {
        float4 v = *(const float4*)&x[base + (size_t)r * ND + c * 4];
        s0 += v.x; s1 += v.y; s2 += v.z; s3 += v.w;
        float p = v.x * v.x + v.y * v.y + v.z * v.z + v.w * v.w;
        q0 += v.x * v.x; q1 += v.y * v.y; q2 += v.z * v.z; q3 += v.w * v.w;
        f16 h0 = (f16)v.x, h1 = (f16)v.y, h2 = (f16)v.z, h3 = (f16)v.w;
        f16x4 hv = {h0, h1, h2, h3};
        f16x4 lv = {(f16)(v.x - (float)h0), (f16)(v.y - (float)h1),
                    (f16)(v.z - (float)h2), (f16)(v.w - (float)h3)};
        *(f16x4*)&xh[base + (size_t)r * ND + c * 4] = hv;
        *(f16x4*)&xl[base + (size_t)r * ND + c * 4] = lv;
        #pragma unroll
        for (int off = 32; off > 0; off >>= 1) p += __shfl_xor(p, off, 64);
        if (c == 0) sq[b * NN + ch * 64 + r] = p;
    }
    __shared__ float rS[4][64][4];
    __shared__ float rQ[4][64][4];
    rS[rg][c][0] = s0; rS[rg][c][1] = s1; rS[rg][c][2] = s2; rS[rg][c][3] = s3;
    rQ[rg][c][0] = q0; rQ[rg][c][1] = q1; rQ[rg][c][2] = q2; rQ[rg][c][3] = q3;
    __syncthreads();
    if (rg == 0) {
        #pragma unroll
        for (int e = 0; e < 4; ++e) {
            float S = rS[0][c][e] + rS[1][c][e] + rS[2][c][e] + rS[3][c][e];
            float Q = rQ[0][c][e] + rQ[1][c][e] + rQ[2][c][e] + rQ[3][c][e];
            partS[(b * 32 + ch) * ND + c * 4 + e] = S;
            partSS[(b * 32 + ch) * ND + c * 4 + e] = Q;
        }
    }
}

// ---- k_scale: sigma -> sc; em[b][n] = exp(-sq*sc) -------------------------
__global__ __launch_bounds__(256) void k_scale(const float* __restrict__ partS,
                                               const float* __restrict__ partSS,
                                               const float* __restrict__ sq,
                                               float* __restrict__ scale,
                                               float* __restrict__ em) {
    int b = blockIdx.x, d = threadIdx.x;
    float s = 0.f, ss = 0.f;
    for (int ch = 0; ch < 32; ++ch) {
        s += partS[(b * 32 + ch) * ND + d];
        ss += partSS[(b * 32 + ch) * ND + d];
    }
    float mean = s * (1.0f / NN);
    float var = ss * (1.0f / NN) - mean * mean;
    float sd = sqrtf(fmaxf(var, 0.f));
    __shared__ float red[256];
    __shared__ float s_sc;
    red[d] = sd;
    __syncthreads();
    for (int off = 128; off > 0; off >>= 1) {
        if (d < off) red[d] += red[d + off];
        __syncthreads();
    }
    if (d == 0) {
        float sigma = red[0] * (1.0f / ND) + EPS;
        double c = pow(4.0 / (ND + 2), 1.0 / (ND + 4)) * pow((double)NN, -1.0 / (ND + 4));
        float h = (float)c * sigma + EPS;
        s_sc = 1.0f / ((float)ND * (2.0f * h * h + EPS));
        scale[b] = s_sc;
    }
    __syncthreads();
    float sc = s_sc;
    for (int n = d; n < NN; n += 256) em[b * NN + n] = __expf(-sq[b * NN + n] * sc);
}

// ---- k_dens: symmetric split-fp16 MFMA GEMM (r2 verified body) ------------
// XCD-pinned 1-D grid: b = wg&7 so each batch's 4.2 MB working set stays in
// one XCD's L2 (r5-verified: FETCH 70 MB -> 8 MB). Single-buffer LDS staging.
__global__ __launch_bounds__(256, 4) void k_dens(const f16* __restrict__ xh,
                                                 const f16* __restrict__ xl,
                                                 const float* __restrict__ em,
                                                 const float* __restrict__ scale,
                                                 float* __restrict__ dens_part) {
    int wg = blockIdx.x;
    int b = wg & 7;          // batch -> XCD pin
    int t = wg >> 3;         // triangular tile index 0..135
    int ti = 0, basec = 0;
    while (t >= basec + (16 - ti)) { basec += 16 - ti; ++ti; }
    int tj = ti + (t - basec);
    int n0 = ti * 128;
    int m0 = tj * 128;

    int tid = threadIdx.x;
    int w = tid >> 6, lane = tid & 63;
    int wr = w >> 1, wc = w & 1;

    __shared__ alignas(16) f16 sAh[128 * 32];
    __shared__ alignas(16) f16 sAl[128 * 32];
    __shared__ alignas(16) f16 sBh[128 * 32];
    __shared__ alignas(16) f16 sBl[128 * 32];
    __shared__ float dl[2][128];
    __shared__ float dc[2][128];

    const size_t xb = (size_t)b * NN * ND;
    const f16* gAh = xh + xb + (size_t)n0 * ND;
    const f16* gAl = xl + xb + (size_t)n0 * ND;
    const f16* gBh = xh + xb + (size_t)m0 * ND;
    const f16* gBl = xl + xb + (size_t)m0 * ND;

    int offA[4], offB[4];
    #pragma unroll
    for (int i = 0; i < 4; ++i) {
        int rA = wr * 64 + i * 16 + (lane & 15);
        offA[i] = rA * 64 + (((lane >> 4) * 16) ^ (((rA >> 1) & 3) << 4));
        int rB = wc * 64 + i * 16 + (lane & 15);
        offB[i] = rB * 64 + (((lane >> 4) * 16) ^ (((rB >> 1) & 3) << 4));
    }

    f32x4 acc[4][4];
    #pragma unroll
    for (int i = 0; i < 4; ++i)
        #pragma unroll
        for (int j = 0; j < 4; ++j)
            acc[i][j] = (f32x4){0.f, 0.f, 0.f, 0.f};

    for (int kt = 0; kt < ND / 32; ++kt) {
        int k0 = kt * 32;
        #pragma unroll
        for (int pass = 0; pass < 2; ++pass) {
            int f = pass * 256 + w * 64 + lane;
            int row = f >> 2;
            int c = f & 3;
            int col = ((c ^ ((row >> 1) & 3)) << 3);
            size_t go = (size_t)row * ND + k0 + col;
            int lo = pass * 2048 + w * 512;
            gload16(gAh + go, sAh + lo);
            gload16(gAl + go, sAl + lo);
            gload16(gBh + go, sBh + lo);
            gload16(gBl + go, sBl + lo);
        }
        __syncthreads();

        f16x8 ah[4], al[4], bh[4], bl[4];
        #pragma unroll
        for (int i = 0; i < 4; ++i) {
            ah[i] = *(const f16x8*)((const char*)sAh + offA[i]);
            al[i] = *(const f16x8*)((const char*)sAl + offA[i]);
            bh[i] = *(const f16x8*)((const char*)sBh + offB[i]);
            bl[i] = *(const f16x8*)((const char*)sBl + offB[i]);
        }
        #pragma unroll
        for (int i = 0; i < 4; ++i)
            #pragma unroll
            for (int j = 0; j < 4; ++j) {
                acc[i][j] = __builtin_amdgcn_mfma_f32_16x16x32_f16(ah[i], bh[j], acc[i][j], 0, 0, 0);
                acc[i][j] = __builtin_amdgcn_mfma_f32_16x16x32_f16(ah[i], bl[j], acc[i][j], 0, 0, 0);
                acc[i][j] = __builtin_amdgcn_mfma_f32_16x16x32_f16(al[i], bh[j], acc[i][j], 0, 0, 0);
            }
        __syncthreads();
    }

    // epilogue: K = exp(2sc*dot); row-part += em[col]*K ; col-part += em[row]*K
    float sc2 = 2.0f * scale[b];
    float emv[4];
    #pragma unroll
    for (int j = 0; j < 4; ++j)
        emv[j] = em[b * NN + m0 + wc * 64 + j * 16 + (lane & 15)];
    float emn[4][4];
    #pragma unroll
    for (int i = 0; i < 4; ++i) {
        float4 v = *(const float4*)&em[b * NN + n0 + wr * 64 + i * 16 + (lane >> 4) * 4];
        emn[i][0] = v.x; emn[i][1] = v.y; emn[i][2] = v.z; emn[i][3] = v.w;
    }

    float colsum[4] = {0.f, 0.f, 0.f, 0.f};
    #pragma unroll
    for (int i = 0; i < 4; ++i)
        #pragma unroll
        for (int e = 0; e < 4; ++e) {
            float rs = 0.f;
            #pragma unroll
            for (int j = 0; j < 4; ++j) {
                float v = __expf(sc2 * acc[i][j][e]);
                rs += emv[j] * v;
                colsum[j] += emn[i][e] * v;
            }
            rs += __shfl_xor(rs, 1, 64);
            rs += __shfl_xor(rs, 2, 64);
            rs += __shfl_xor(rs, 4, 64);
            rs += __shfl_xor(rs, 8, 64);
            if ((lane & 15) == 0)
                dl[wc][wr * 64 + i * 16 + (lane >> 4) * 4 + e] = rs;
        }
    #pragma unroll
    for (int j = 0; j < 4; ++j) {
        float cs = colsum[j];
        cs += __shfl_xor(cs, 16, 64);
        cs += __shfl_xor(cs, 32, 64);
        if ((lane >> 4) == 0)
            dc[wr][wc * 64 + j * 16 + (lane & 15)] = cs;
    }
    __syncthreads();
    if (tid < 128) {
        dens_part[((size_t)(b * 16) + tj) * NN + n0 + tid] = dl[0][tid] + dl[1][tid];
    } else if (ti != tj) {
        int c = tid - 128;
        dens_part[((size_t)(b * 16) + ti) * NN + m0 + c] = dc[0][c] + dc[1][c];
    }
}

// ---- k_dsum: dens = em*sum(16 partials) + per-block density sum -----------
__global__ __launch_bounds__(256) void k_dsum(const float* __restrict__ part,
                                              const float* __restrict__ em,
                                              float* __restrict__ dens,
                                              float* __restrict__ psum) {
    int b = blockIdx.y;
    int n = blockIdx.x * 256 + threadIdx.x;
    int t = threadIdx.x;
    float s = 0.f;
    #pragma unroll
    for (int mt = 0; mt < 16; ++mt) s += part[((size_t)(b * 16 + mt)) * NN + n];
    s *= em[b * NN + n];
    dens[b * NN + n] = s;
    __shared__ float red[256];
    red[t] = s;
    __syncthreads();
    for (int off = 128; off > 0; off >>= 1) {
        if (t < off) red[t] += red[t + off];
        __syncthreads();
    }
    if (t == 0) psum[b * 8 + blockIdx.x] = red[0];
}

// ---- k_maskstat: per-block stats (mean from psum, var over L2-hot dens),
//      then masked partial feature sums. grid (16, NB). ----------------------
__global__ __launch_bounds__(256) void k_maskstat(const float* __restrict__ x,
                                                  const float* __restrict__ dens,
                                                  const float* __restrict__ psum,
                                                  float* __restrict__ partM,
                                                  int* __restrict__ partC) {
    int b = blockIdx.y, ch = blockIdx.x;
    int t = threadIdx.x;
    int c = t & 63, rg = t >> 6;

    // stats: mean from psum; two-pass ddof=1 var over dens (8 KB, L2-hot)
    float tot = 0.f;
    #pragma unroll
    for (int i = 0; i < 8; ++i) tot += psum[b * 8 + i];
    float mean = tot * (1.0f / NN);
    float vs = 0.f;
    #pragma unroll
    for (int i = 0; i < 8; ++i) {
        float d2 = dens[b * NN + t + i * 256] - mean;
        vs += d2 * d2;
    }
    __shared__ float red[256];
    __shared__ float s_thr;
    red[t] = vs;
    __syncthreads();
    for (int off = 128; off > 0; off >>= 1) {
        if (t < off) red[t] += red[t + off];
        __syncthreads();
    }
    if (t == 0) s_thr = mean - 2.0f * sqrtf(red[0] / (float)(NN - 1));
    __syncthreads();
    float tv = s_thr;

    float s0 = 0.f, s1 = 0.f, s2 = 0.f, s3 = 0.f;
    int cnt = 0;
    for (int r = rg; r < 128; r += 4) {
        int n = ch * 128 + r;
        if (dens[b * NN + n] > tv) {     // wave-uniform (one rowgroup per wave)
            float4 v = *(const float4*)&x[((size_t)b * NN + n) * ND + c * 4];
            s0 += v.x; s1 += v.y; s2 += v.z; s3 += v.w;
            ++cnt;
        }
    }
    __shared__ float rS[4][64][4];
    __shared__ int rC[4];
    rS[rg][c][0] = s0; rS[rg][c][1] = s1; rS[rg][c][2] = s2; rS[rg][c][3] = s3;
    if (c == 0) rC[rg] = cnt;
    __syncthreads();
    if (rg == 0) {
        #pragma unroll
        for (int e = 0; e < 4; ++e) {
            float S = rS[0][c][e] + rS[1][c][e] + rS[2][c][e] + rS[3][c][e];
            partM[(b * 16 + ch) * ND + c * 4 + e] = S;
        }
        if (c == 0) partC[b * 16 + ch] = rC[0] + rC[1] + rC[2] + rC[3];
    }
}

// ---- k_out: combine --------------------------------------------------------
__global__ __launch_bounds__(256) void k_out(const float* __restrict__ partM,
                                             const int* __restrict__ partC,
                                             float* __restrict__ out) {
    int b = blockIdx.x, d = threadIdx.x;
    float s = 0.f;
    int cnt = 0;
    for (int ch = 0; ch < 16; ++ch) {
        s += partM[(b * 16 + ch) * ND + d];
        cnt += partC[b * 16 + ch];
    }
    out[b * ND + d] = (cnt > 0) ? s / (float)max(cnt, 1) : 0.f;
}

extern "C" void kernel_launch(void* const* d_in, const int* in_sizes, int n_in,
                              void* d_out, int out_size, void* d_ws, size_t ws_size,
                              hipStream_t stream) {
    const float* x = (const float*)d_in[0];
    float* out = (float*)d_out;

    char* p = (char*)d_ws;
    f16* xh = (f16*)p;            p += (size_t)NB * NN * ND * 2;
    f16* xl = (f16*)p;            p += (size_t)NB * NN * ND * 2;
    float* sq = (float*)p;        p += (size_t)NB * NN * 4;
    float* em = (float*)p;        p += (size_t)NB * NN * 4;
    float* partS = (float*)p;     p += (size_t)NB * 32 * ND * 4;
    float* partSS = (float*)p;    p += (size_t)NB * 32 * ND * 4;
    float* scale = (float*)p;     p += 256;
    float* dens_part = (float*)p; p += (size_t)NB * 16 * NN * 4;
    float* dens = (float*)p;      p += (size_t)NB * NN * 4;
    float* psum = (float*)p;      p += 256;
    float* partM = (float*)p;     p += (size_t)NB * 16 * ND * 4;
    int* partC = (int*)p;         p += (size_t)NB * 16 * 4;

    k_prep<<<dim3(32, NB), 256, 0, stream>>>(x, xh, xl, partS, partSS, sq);
    k_scale<<<NB, 256, 0, stream>>>(partS, partSS, sq, scale, em);
    k_dens<<<136 * NB, 256, 0, stream>>>(xh, xl, em, scale, dens_part);
    k_dsum<<<dim3(8, NB), 256, 0, stream>>>(dens_part, em, dens, psum);
    k_maskstat<<<dim3(16, NB), 256, 0, stream>>>(x, dens, psum, partM, partC);
    k_out<<<NB, 256, 0, stream>>>(partM, partC, out);
}

// Round 8
// 66.563 us; speedup vs baseline: 1.8845x; 1.2803x over previous
//
#include <hip/hip_runtime.h>
#include <math.h>

#define NB 8
#define NN 2048
#define ND 256

typedef _Float16 f16;
typedef f16 f16x8 __attribute__((ext_vector_type(8)));
typedef f16 f16x4 __attribute__((ext_vector_type(4)));
typedef float f32x4 __attribute__((ext_vector_type(4)));

static constexpr float EPS = 1e-6f;

__device__ __forceinline__ void gload16(const void* g, void* l) {
    __builtin_amdgcn_global_load_lds(
        (const __attribute__((address_space(1))) unsigned int*)g,
        (__attribute__((address_space(3))) unsigned int*)l, 16, 0, 0);
}

// ---- k_prep: x -> (hi,lo) fp16 split + partial sum/sumsq + row norms ------
__global__ __launch_bounds__(256) void k_prep(const float* __restrict__ x,
                                              f16* __restrict__ xh, f16* __restrict__ xl,
                                              float* __restrict__ partS,
                                              float* __restrict__ partSS,
                                              float* __restrict__ sq) {
    int b = blockIdx.y, ch = blockIdx.x;
    int t = threadIdx.x;
    int c = t & 63, rg = t >> 6;
    size_t base = ((size_t)b * NN + (size_t)ch * 64) * ND;
    float s0 = 0.f, s1 = 0.f, s2 = 0.f, s3 = 0.f;
    float q0 = 0.f, q1 = 0.f, q2 = 0.f, q3 = 0.f;
    for (int r = rg; r < 64; r += 4) {
        float4 v = *(const float4*)&x[base + (size_t)r * ND + c * 4];
        s0 += v.x; s1 += v.y; s2 += v.z; s3 += v.w;
        float p = v.x * v.x + v.y * v.y + v.z * v.z + v.w * v.w;
        q0 += v.x * v.x; q1 += v.y * v.y; q2 += v.z * v.z; q3 += v.w * v.w;
        f16 h0 = (f16)v.x, h1 = (f16)v.y, h2 = (f16)v.z, h3 = (f16)v.w;
        f16x4 hv = {h0, h1, h2, h3};
        f16x4 lv = {(f16)(v.x - (float)h0), (f16)(v.y - (float)h1),
                    (f16)(v.z - (float)h2), (f16)(v.w - (float)h3)};
        *(f16x4*)&xh[base + (size_t)r * ND + c * 4] = hv;
        *(f16x4*)&xl[base + (size_t)r * ND + c * 4] = lv;
        #pragma unroll
        for (int off = 32; off > 0; off >>= 1) p += __shfl_xor(p, off, 64);
        if (c == 0) sq[b * NN + ch * 64 + r] = p;
    }
    __shared__ float rS[4][64][4];
    __shared__ float rQ[4][64][4];
    rS[rg][c][0] = s0; rS[rg][c][1] = s1; rS[rg][c][2] = s2; rS[rg][c][3] = s3;
    rQ[rg][c][0] = q0; rQ[rg][c][1] = q1; rQ[rg][c][2] = q2; rQ[rg][c][3] = q3;
    __syncthreads();
    if (rg == 0) {
        #pragma unroll
        for (int e = 0; e < 4; ++e) {
            float S = rS[0][c][e] + rS[1][c][e] + rS[2][c][e] + rS[3][c][e];
            float Q = rQ[0][c][e] + rQ[1][c][e] + rQ[2][c][e] + rQ[3][c][e];
            partS[(b * 32 + ch) * ND + c * 4 + e] = S;
            partSS[(b * 32 + ch) * ND + c * 4 + e] = Q;
        }
    }
}

// ---- k_scale: sigma -> sc; em[b][n] = exp(-sq*sc) -------------------------
__global__ __launch_bounds__(256) void k_scale(const float* __restrict__ partS,
                                               const float* __restrict__ partSS,
                                               const float* __restrict__ sq,
                                               float* __restrict__ scale,
                                               float* __restrict__ em) {
    int b = blockIdx.x, d = threadIdx.x;
    float s = 0.f, ss = 0.f;
    for (int ch = 0; ch < 32; ++ch) {
        s += partS[(b * 32 + ch) * ND + d];
        ss += partSS[(b * 32 + ch) * ND + d];
    }
    float mean = s * (1.0f / NN);
    float var = ss * (1.0f / NN) - mean * mean;
    float sd = sqrtf(fmaxf(var, 0.f));
    __shared__ float red[256];
    __shared__ float s_sc;
    red[d] = sd;
    __syncthreads();
    for (int off = 128; off > 0; off >>= 1) {
        if (d < off) red[d] += red[d + off];
        __syncthreads();
    }
    if (d == 0) {
        float sigma = red[0] * (1.0f / ND) + EPS;
        double c = pow(4.0 / (ND + 2), 1.0 / (ND + 4)) * pow((double)NN, -1.0 / (ND + 4));
        float h = (float)c * sigma + EPS;
        s_sc = 1.0f / ((float)ND * (2.0f * h * h + EPS));
        scale[b] = s_sc;
    }
    __syncthreads();
    float sc = s_sc;
    for (int n = d; n < NN; n += 256) em[b * NN + n] = __expf(-sq[b * NN + n] * sc);
}

// ---- k_dens: symmetric asymmetric-split MFMA GEMM, BK=64, 3 LDS tiles -----
// dot(n,m) ~= h_n.h_m + h_n.l_m = <fp16(x_n), x_m>. Only 3 tiles staged
// (A-hi, B-hi, B-lo); BK=64 halves barrier-drain count. XCD-pinned grid.
__global__ __launch_bounds__(256, 3) void k_dens(const f16* __restrict__ xh,
                                                 const f16* __restrict__ xl,
                                                 const float* __restrict__ em,
                                                 const float* __restrict__ scale,
                                                 float* __restrict__ dens_part) {
    int wg = blockIdx.x;
    int b = wg & 7;          // batch -> XCD pin
    int t = wg >> 3;         // triangular tile index 0..135
    int ti = 0, basec = 0;
    while (t >= basec + (16 - ti)) { basec += 16 - ti; ++ti; }
    int tj = ti + (t - basec);
    int n0 = ti * 128;
    int m0 = tj * 128;

    int tid = threadIdx.x;
    int w = tid >> 6, lane = tid & 63;
    int wr = w >> 1, wc = w & 1;

    __shared__ alignas(16) f16 sAh[128 * 64];
    __shared__ alignas(16) f16 sBh[128 * 64];
    __shared__ alignas(16) f16 sBl[128 * 64];
    __shared__ float dl[2][128];
    __shared__ float dc[2][128];

    const size_t xb = (size_t)b * NN * ND;
    const f16* gAh = xh + xb + (size_t)n0 * ND;
    const f16* gBh = xh + xb + (size_t)m0 * ND;
    const f16* gBl = xl + xb + (size_t)m0 * ND;

    // ds_read byte offsets: row stride 128B; 16B chunk q XOR-swizzled by row&7
    int offA[4], offB[4];
    #pragma unroll
    for (int i = 0; i < 4; ++i) {
        int rA = wr * 64 + i * 16 + (lane & 15);
        offA[i] = rA * 128 + ((((lane >> 4) ^ (rA & 7))) << 4);
        int rB = wc * 64 + i * 16 + (lane & 15);
        offB[i] = rB * 128 + ((((lane >> 4) ^ (rB & 7))) << 4);
    }

    f32x4 acc[4][4];
    #pragma unroll
    for (int i = 0; i < 4; ++i)
        #pragma unroll
        for (int j = 0; j < 4; ++j)
            acc[i][j] = (f32x4){0.f, 0.f, 0.f, 0.f};

    for (int kt = 0; kt < ND / 64; ++kt) {
        int k0 = kt * 64;
        // stage 3 tiles: linear LDS dest, inverse-swizzled global source
        #pragma unroll
        for (int p = 0; p < 4; ++p) {
            int f = p * 256 + w * 64 + lane;     // 16B-chunk index 0..1023
            int row = f >> 3;                    // 0..127
            int c = f & 7;
            int col = ((c ^ (row & 7)) << 3);    // f16 col within BK=64
            size_t go = (size_t)row * ND + k0 + col;
            int lo = p * 2048 + w * 512;         // f16 units, wave-uniform
            gload16(gAh + go, sAh + lo);
            gload16(gBh + go, sBh + lo);
            gload16(gBl + go, sBl + lo);
        }
        __syncthreads();

        #pragma unroll
        for (int kk = 0; kk < 2; ++kk) {
            int dx = kk << 6;                    // q+4 == byte-offset ^ 64
            f16x8 ah[4], bh[4], bl[4];
            #pragma unroll
            for (int i = 0; i < 4; ++i) {
                ah[i] = *(const f16x8*)((const char*)sAh + (offA[i] ^ dx));
                bh[i] = *(const f16x8*)((const char*)sBh + (offB[i] ^ dx));
                bl[i] = *(const f16x8*)((const char*)sBl + (offB[i] ^ dx));
            }
            #pragma unroll
            for (int i = 0; i < 4; ++i)
                #pragma unroll
                for (int j = 0; j < 4; ++j) {
                    acc[i][j] = __builtin_amdgcn_mfma_f32_16x16x32_f16(ah[i], bh[j], acc[i][j], 0, 0, 0);
                    acc[i][j] = __builtin_amdgcn_mfma_f32_16x16x32_f16(ah[i], bl[j], acc[i][j], 0, 0, 0);
                }
        }
        __syncthreads();
    }

    // epilogue: K = exp(2sc*dot); row-part += em[col]*K ; col-part += em[row]*K
    float sc2 = 2.0f * scale[b];
    float emv[4];
    #pragma unroll
    for (int j = 0; j < 4; ++j)
        emv[j] = em[b * NN + m0 + wc * 64 + j * 16 + (lane & 15)];
    float emn[4][4];
    #pragma unroll
    for (int i = 0; i < 4; ++i) {
        float4 v = *(const float4*)&em[b * NN + n0 + wr * 64 + i * 16 + (lane >> 4) * 4];
        emn[i][0] = v.x; emn[i][1] = v.y; emn[i][2] = v.z; emn[i][3] = v.w;
    }

    float colsum[4] = {0.f, 0.f, 0.f, 0.f};
    #pragma unroll
    for (int i = 0; i < 4; ++i)
        #pragma unroll
        for (int e = 0; e < 4; ++e) {
            float rs = 0.f;
            #pragma unroll
            for (int j = 0; j < 4; ++j) {
                float v = __expf(sc2 * acc[i][j][e]);
                rs += emv[j] * v;
                colsum[j] += emn[i][e] * v;
            }
            rs += __shfl_xor(rs, 1, 64);
            rs += __shfl_xor(rs, 2, 64);
            rs += __shfl_xor(rs, 4, 64);
            rs += __shfl_xor(rs, 8, 64);
            if ((lane & 15) == 0)
                dl[wc][wr * 64 + i * 16 + (lane >> 4) * 4 + e] = rs;
        }
    #pragma unroll
    for (int j = 0; j < 4; ++j) {
        float cs = colsum[j];
        cs += __shfl_xor(cs, 16, 64);
        cs += __shfl_xor(cs, 32, 64);
        if ((lane >> 4) == 0)
            dc[wr][wc * 64 + j * 16 + (lane & 15)] = cs;
    }
    __syncthreads();
    if (tid < 128) {
        dens_part[((size_t)(b * 16) + tj) * NN + n0 + tid] = dl[0][tid] + dl[1][tid];
    } else if (ti != tj) {
        int c = tid - 128;
        dens_part[((size_t)(b * 16) + ti) * NN + m0 + c] = dc[0][c] + dc[1][c];
    }
}

// ---- k_maskstat: dens from partials (in-reg), mean/std(ddof=1), mask sums -
// grid (16, NB). Each block recomputes all 2048 densities from L2-hot
// dens_part (128 KB), derives thr, then masks its own 128-row chunk.
__global__ __launch_bounds__(256) void k_maskstat(const float* __restrict__ x,
                                                  const float* __restrict__ part,
                                                  const float* __restrict__ em,
                                                  float* __restrict__ partM,
                                                  int* __restrict__ partC) {
    int b = blockIdx.y, ch = blockIdx.x;
    int t = threadIdx.x;
    int c = t & 63, rg = t >> 6;

    float dloc[8];
    float s = 0.f;
    #pragma unroll
    for (int i = 0; i < 8; ++i) {
        int n = t + i * 256;
        float v = 0.f;
        #pragma unroll
        for (int mt = 0; mt < 16; ++mt) v += part[((size_t)(b * 16 + mt)) * NN + n];
        v *= em[b * NN + n];
        dloc[i] = v;
        s += v;
    }
    __shared__ float red[256];
    __shared__ float s_thr;
    __shared__ float sD[128];
    red[t] = s;
    __syncthreads();
    for (int off = 128; off > 0; off >>= 1) {
        if (t < off) red[t] += red[t + off];
        __syncthreads();
    }
    float mean = red[0] * (1.0f / NN);
    __syncthreads();
    float vs = 0.f;
    #pragma unroll
    for (int i = 0; i < 8; ++i) {
        float d2 = dloc[i] - mean;
        vs += d2 * d2;
    }
    red[t] = vs;
    // own-chunk densities -> LDS: chunk rows [ch*128, ch*128+128) live in
    // stripe i0 = ch>>1 at threads t in [(ch&1)*128, (ch&1)*128+128)
    {
        int i0 = ch >> 1;
        int tlo = (ch & 1) * 128;
        if (t >= tlo && t < tlo + 128) sD[t - tlo] = dloc[i0];
    }
    __syncthreads();
    for (int off = 128; off > 0; off >>= 1) {
        if (t < off) red[t] += red[t + off];
        __syncthreads();
    }
    if (t == 0) s_thr = mean - 2.0f * sqrtf(red[0] / (float)(NN - 1));
    __syncthreads();
    float tv = s_thr;

    float s0 = 0.f, s1 = 0.f, s2 = 0.f, s3 = 0.f;
    int cnt = 0;
    for (int r = rg; r < 128; r += 4) {
        int n = ch * 128 + r;
        if (sD[r] > tv) {                // wave-uniform (one rowgroup per wave)
            float4 v = *(const float4*)&x[((size_t)b * NN + n) * ND + c * 4];
            s0 += v.x; s1 += v.y; s2 += v.z; s3 += v.w;
            ++cnt;
        }
    }
    __shared__ float rS[4][64][4];
    __shared__ int rC[4];
    rS[rg][c][0] = s0; rS[rg][c][1] = s1; rS[rg][c][2] = s2; rS[rg][c][3] = s3;
    if (c == 0) rC[rg] = cnt;
    __syncthreads();
    if (rg == 0) {
        #pragma unroll
        for (int e = 0; e < 4; ++e) {
            float S = rS[0][c][e] + rS[1][c][e] + rS[2][c][e] + rS[3][c][e];
            partM[(b * 16 + ch) * ND + c * 4 + e] = S;
        }
        if (c == 0) partC[b * 16 + ch] = rC[0] + rC[1] + rC[2] + rC[3];
    }
}

// ---- k_out: combine --------------------------------------------------------
__global__ __launch_bounds__(256) void k_out(const float* __restrict__ partM,
                                             const int* __restrict__ partC,
                                             float* __restrict__ out) {
    int b = blockIdx.x, d = threadIdx.x;
    float s = 0.f;
    int cnt = 0;
    for (int ch = 0; ch < 16; ++ch) {
        s += partM[(b * 16 + ch) * ND + d];
        cnt += partC[b * 16 + ch];
    }
    out[b * ND + d] = (cnt > 0) ? s / (float)max(cnt, 1) : 0.f;
}

extern "C" void kernel_launch(void* const* d_in, const int* in_sizes, int n_in,
                              void* d_out, int out_size, void* d_ws, size_t ws_size,
                              hipStream_t stream) {
    const float* x = (const float*)d_in[0];
    float* out = (float*)d_out;

    char* p = (char*)d_ws;
    f16* xh = (f16*)p;            p += (size_t)NB * NN * ND * 2;
    f16* xl = (f16*)p;            p += (size_t)NB * NN * ND * 2;
    float* sq = (float*)p;        p += (size_t)NB * NN * 4;
    float* em = (float*)p;        p += (size_t)NB * NN * 4;
    float* partS = (float*)p;     p += (size_t)NB * 32 * ND * 4;
    float* partSS = (float*)p;    p += (size_t)NB * 32 * ND * 4;
    float* scale = (float*)p;     p += 256;
    float* dens_part = (float*)p; p += (size_t)NB * 16 * NN * 4;
    float* partM = (float*)p;     p += (size_t)NB * 16 * ND * 4;
    int* partC = (int*)p;         p += (size_t)NB * 16 * 4;

    k_prep<<<dim3(32, NB), 256, 0, stream>>>(x, xh, xl, partS, partSS, sq);
    k_scale<<<NB, 256, 0, stream>>>(partS, partSS, sq, scale, em);
    k_dens<<<136 * NB, 256, 0, stream>>>(xh, xl, em, scale, dens_part);
    k_maskstat<<<dim3(16, NB), 256, 0, stream>>>(x, dens_part, em, partM, partC);
    k_out<<<NB, 256, 0, stream>>>(partM, partC, out);
}